// Round 10
// baseline (8008.617 us; speedup 1.0000x reference)
//
#include <hip/hip_runtime.h>

#define FF 512
#define HH 1024
#define LL 128
#define BB 128
#define PP 1024

typedef short short8 __attribute__((ext_vector_type(8)));
typedef float floatx4 __attribute__((ext_vector_type(4)));
typedef unsigned short ushort_t;
typedef unsigned long long u64;

__device__ __forceinline__ float sigm(float x) {
    return 1.0f / (1.0f + __expf(-x));
}
// overflow-safe tanh: exp(-2|x|) underflows to 0 for large |x| -> +-1
__device__ __forceinline__ float tanh_fast(float x) {
    float ax = fabsf(x);
    float e = __expf(-2.0f * ax);
    float r = (1.0f - e) / (1.0f + e);
    return copysignf(r, x);
}

__device__ __forceinline__ unsigned short bf16_rtne(float x) {
    unsigned int u = __float_as_uint(x);
    return (unsigned short)((u + 0x7FFFu + ((u >> 16) & 1u)) >> 16);
}
__device__ __forceinline__ void split_bf16(float x, unsigned short& hi, unsigned short& lo) {
    hi = bf16_rtne(x);
    float hf = __uint_as_float(((unsigned int)hi) << 16);
    lo = bf16_rtne(x - hf);
}

// --- agent-scope h exchange: coherent across XCDs (verified R3/R4/R8) ---
__device__ __forceinline__ int4 ld_h16(const ushort_t* p) {
    u64* q = (u64*)p;
    u64 a = __hip_atomic_load(q,     __ATOMIC_RELAXED, __HIP_MEMORY_SCOPE_AGENT);
    u64 b = __hip_atomic_load(q + 1, __ATOMIC_RELAXED, __HIP_MEMORY_SCOPE_AGENT);
    return make_int4((int)(unsigned)(a & 0xffffffffull), (int)(unsigned)(a >> 32),
                     (int)(unsigned)(b & 0xffffffffull), (int)(unsigned)(b >> 32));
}
__device__ __forceinline__ void st_h8(ushort_t* p, uint2 v) {
    u64 x = ((u64)v.y << 32) | (u64)v.x;
    __hip_atomic_store((u64*)p, x, __ATOMIC_RELAXED, __HIP_MEMORY_SCOPE_AGENT);
}
__device__ __forceinline__ float4 ld_f4_bypass(const float* p) {
    u64* q = (u64*)p;
    u64 a = __hip_atomic_load(q,     __ATOMIC_RELAXED, __HIP_MEMORY_SCOPE_AGENT);
    u64 b = __hip_atomic_load(q + 1, __ATOMIC_RELAXED, __HIP_MEMORY_SCOPE_AGENT);
    float4 r;
    ((u64*)&r)[0] = a;
    ((u64*)&r)[1] = b;
    return r;
}

// monotonic-counter grid barrier (VERIFIED R3/R4/R8)
__device__ __forceinline__ void grid_barrier(unsigned* cnt, unsigned target, int tid) {
    __syncthreads();
    if (tid == 0) {
        __hip_atomic_fetch_add(cnt, 1u, __ATOMIC_RELAXED, __HIP_MEMORY_SCOPE_AGENT);
        while (__hip_atomic_load(cnt, __ATOMIC_RELAXED, __HIP_MEMORY_SCOPE_AGENT) < target) {
            __builtin_amdgcn_s_sleep(2);
        }
    }
    __syncthreads();
}

__global__ void fillz(float* p, int n) {
    int i = blockIdx.x * blockDim.x + threadIdx.x;
    if (i < n) p[i] = 0.0f;
}

// fp32 [n] -> bf16 (RTNE) [n]
__global__ void round_w(const float* __restrict__ W, ushort_t* __restrict__ hi, int n) {
    int i = blockIdx.x * blockDim.x + threadIdx.x;
    if (i < n) hi[i] = bf16_rtne(W[i]);
}

// ---------------------------------------------------------------------------
// Persistent cooperative encoder, v7 (half-W LDS-resident):
// R3/R4/R8 law: encoder dur == FETCH_bytes / ~590 GB/s; biggest FETCH term
// is the 8 MB/step W_hi re-stream. Fix: per block, gates 0-1's W rows
// (64 x 1024 bf16 = 128 KB) live in LDS for a whole 128-step phase
// (preloaded at t=0 and t=128); gates 2-3 keep the verified streamed-B
// path (4 MB/step FETCH). LDS = W 128 KB + A dbuf 32 KB = 160 KB dynamic,
// 1 block/CU (grid 256 = 1/CU already).
// Wave layout: 8 waves = (gate g, n-half nh); each wave 64f x 16n for ONE
// gate, full serial K=1024 (16 chunks of 64) -> no kh-reduce; single Gx
// write (stride 32, aliases A dbuf post-loop).
// UNCHANGED from verified R8: grid 256x512, XCD decode, A staging + rotate
// swizzle, reg-prefetch/write-after-compute pipeline, agent-atomic h
// exchange, counter barrier, epilogue mapping, 2-term (h_hi+h_lo) x W.
// ---------------------------------------------------------------------------
__global__ __launch_bounds__(512, 1) void lstm_encoder_persistent(
    ushort_t* __restrict__ hhiA, ushort_t* __restrict__ hloA,   // buf0 (zeroed)
    ushort_t* __restrict__ hhiB, ushort_t* __restrict__ hloB,   // buf1
    float* __restrict__ h_fin,   // fp32 final h   (h_a)
    float* __restrict__ c_fin,   // fp32 final c   (c_st)
    const ushort_t* __restrict__ Whi1,
    const ushort_t* __restrict__ Whi2,
    const float* __restrict__ emb1, const float* __restrict__ emb2,
    const int* __restrict__ tok1, const int* __restrict__ len1,
    const int* __restrict__ tok2, const int* __restrict__ len2,
    unsigned* __restrict__ barCnt)
{
    // dynamic LDS 163840 B:
    //   W resident: [0, 131072)   64 rows x 1024 bf16, 16B-unit XOR swizzle
    //   A regions:  [131072, 163840): parity p: hi @ +p*16384, lo @ +p*16384+8192
    //   Gx (post-loop alias of A): [131072, +32768) = 4 gates x 64 f x 32 c fp32
    extern __shared__ __align__(16) int4 smem4[];
    char* smem = (char*)smem4;
    char* Wlds  = smem;
    char* Abase = smem + 131072;
    float* Gx = (float*)Abase;

    const int tid = threadIdx.x;
    const int w = tid >> 6;              // wave 0..7
    const int l = tid & 63;
    const int q = l >> 4;                // k-quad 0..3
    const int fr = l & 15;               // fragment row/col
    const int nh = w & 1;                // n-half 0/1
    const bool ldsW = (w < 4);           // waves 0-3: gates 0,1 from LDS
    const int g = ldsW ? (w >> 1) : (2 + ((w >> 1) & 1));

    // XCD-aware decode (VERIFIED): xcd = id&7
    const int id = blockIdx.x;
    const int by = (id & 7) + 8 * ((id >> 3) & 3);
    const int bx = id >> 5;
    const int fbase = bx * 64;
    const int n0 = by * 32;

    // --- A staging map: 512 thr x (16B hi + 16B lo) per chunk ---
    const int ar = tid >> 3;             // row 0..63
    const int s0 = tid & 7;              // slot 0..7
    const size_t a_goff = (size_t)(fbase + ar) * HH + s0 * 8;
    const int ldsIdx = ar * 8 + ((s0 + ar) & 7);

    // --- W preload map (128 KB, 16 x int4 per thread) ---
    const int pw_row = tid >> 3;         // local W row 0..63
    const int pw_colb = (tid & 7) * 128; // + j*8
    const size_t pw_grow = (size_t)((pw_row >> 5) * 1024 + n0 + (pw_row & 31)) * HH;

    // --- streamed-B offsets (waves 4..7) ---
    const size_t brow = ((size_t)g * HH + n0 + nh * 16 + fr) * HH + q * 8;

    // --- W-LDS fragment row (waves 0..3) ---
    const int wrow = (w >> 1) * 32 + nh * 16 + fr;   // 0..63

    // --- epilogue map + persistent cell state ---
    const int rr = tid >> 3;
    const int c0 = (tid & 7) * 4;
    const int f = fbase + rr;
    const int gc = n0 + c0;
    const size_t gidx = (size_t)f * HH + gc;
    float4 creg = make_float4(0.f, 0.f, 0.f, 0.f);
    float4 hreg = make_float4(0.f, 0.f, 0.f, 0.f);

    // streamed-B double buffer [parity][kk]; prefetch chunk0 of t=0
    short8 Bs[2][2];
    if (!ldsW) {
        Bs[0][0] = *(const short8*)(Whi1 + brow);
        Bs[0][1] = *(const short8*)(Whi1 + brow + 32);
    }

    for (int t = 0; t < 256; ++t) {
        const int tt = t & 127;
        const bool ph2 = t >= 128;
        const ushort_t* Wh = ph2 ? Whi2 : Whi1;
        const ushort_t* WhN = (t >= 127) ? Whi2 : Whi1;  // base for t+1
        const float* emb = ph2 ? emb2 : emb1;
        const int* tok = ph2 ? tok2 : tok1;
        const int* len = ph2 ? len2 : len1;
        const ushort_t* rhh = (t & 1) ? hhiB : hhiA;
        const ushort_t* rhl = (t & 1) ? hloB : hloA;
        ushort_t* whh = (t & 1) ? hhiA : hhiB;
        ushort_t* whl = (t & 1) ? hloA : hloB;

        // phase start: (re)load resident W gates 0-1 into LDS (once/128 steps)
        if (tt == 0) {
            #pragma unroll
            for (int j = 0; j < 16; ++j) {
                const int col = pw_colb + j * 8;
                int4 v = *(const int4*)(Wh + pw_grow + col);
                const int unit = col >> 3;                      // 0..127
                const int swz = (unit & ~7) | ((unit ^ pw_row) & 7);
                *(int4*)(Wlds + pw_row * 2048 + swz * 16) = v;
            }
        }

        // A chunk 0 -> LDS parity 0 (agent-scope bypass loads)
        {
            int4 h0 = ld_h16(rhh + a_goff);
            int4 l0v = ld_h16(rhl + a_goff);
            ((int4*)Abase)[ldsIdx] = h0;
            ((int4*)(Abase + 8192))[ldsIdx] = l0v;
        }
        __syncthreads();

        floatx4 acc[4];
        #pragma unroll
        for (int m = 0; m < 4; ++m) acc[m] = (floatx4)(0.0f);

        int4 pa_h, pa_l;
        #pragma unroll 2
        for (int i = 0; i < 16; ++i) {
            const int cur = i & 1, nxt = cur ^ 1;
            const char* AsH = Abase + cur * 16384;
            const char* AsL = AsH + 8192;

            // A prefetch for chunk i+1 (regs; written to LDS after compute)
            if (i < 15) {
                const int k0 = (i + 1) * 64;
                pa_h = ld_h16(rhh + a_goff + k0);
                pa_l = ld_h16(rhl + a_goff + k0);
            }
            // streamed-B prefetch: chunks 1..15, or chunk0 of NEXT step at i==15
            if (!ldsW) {
                const ushort_t* Bp = (i < 15) ? Wh : WhN;
                const int k0 = (i < 15) ? (i + 1) * 64 : 0;
                Bs[nxt][0] = *(const short8*)(Bp + brow + k0);
                Bs[nxt][1] = *(const short8*)(Bp + brow + k0 + 32);
            }

            // W fragments for this chunk
            short8 w0, w1;
            if (ldsW) {
                const int u0 = i * 8 + q;        // kk=0 unit
                const int u1 = i * 8 + 4 + q;    // kk=1 unit
                w0 = *(const short8*)(Wlds + wrow * 2048 + ((u0 & ~7) | ((u0 ^ wrow) & 7)) * 16);
                w1 = *(const short8*)(Wlds + wrow * 2048 + ((u1 & ~7) | ((u1 ^ wrow) & 7)) * 16);
            } else {
                w0 = Bs[cur][0];
                w1 = Bs[cur][1];
            }

            // compute chunk i: 2-term (h_hi + h_lo) x W, 16 MFMA/wave
            #pragma unroll
            for (int m = 0; m < 4; ++m) {
                const int r = m * 16 + fr;
                short8 ah0 = *(const short8*)(AsH + (r * 8 + ((0 + q + r) & 7)) * 16);
                short8 ah1 = *(const short8*)(AsH + (r * 8 + ((4 + q + r) & 7)) * 16);
                short8 al0 = *(const short8*)(AsL + (r * 8 + ((0 + q + r) & 7)) * 16);
                short8 al1 = *(const short8*)(AsL + (r * 8 + ((4 + q + r) & 7)) * 16);
                acc[m] = __builtin_amdgcn_mfma_f32_16x16x32_bf16(ah0, w0, acc[m], 0, 0, 0);
                acc[m] = __builtin_amdgcn_mfma_f32_16x16x32_bf16(al0, w0, acc[m], 0, 0, 0);
                acc[m] = __builtin_amdgcn_mfma_f32_16x16x32_bf16(ah1, w1, acc[m], 0, 0, 0);
                acc[m] = __builtin_amdgcn_mfma_f32_16x16x32_bf16(al1, w1, acc[m], 0, 0, 0);
            }

            if (i < 15) {
                char* DH = Abase + nxt * 16384;
                ((int4*)DH)[ldsIdx] = pa_h;
                ((int4*)(DH + 8192))[ldsIdx] = pa_l;
            }
            __syncthreads();
        }

        // --- Gx write (single pass; each wave owns full-K result for its
        //     gate x n-half). C/D layout: col=fr, row=q*4+reg. stride 32.
        #pragma unroll
        for (int m = 0; m < 4; ++m)
            #pragma unroll
            for (int r = 0; r < 4; ++r)
                Gx[g * 2048 + (m * 16 + q * 4 + r) * 32 + nh * 16 + fr] = acc[m][r];
        __syncthreads();

        // --- fused cell update; c and mask-h in registers ---
        const float* ib = emb + (size_t)tok[f * LL + tt] * 4096;
        const bool upd = tt < len[f];

        float4 gv[4];
        #pragma unroll
        for (int gg = 0; gg < 4; ++gg) {
            gv[gg] = *(const float4*)&Gx[gg * 2048 + rr * 32 + c0];
            const float4 ibv = ld_f4_bypass(ib + gg * 1024 + gc);
            gv[gg].x += ibv.x; gv[gg].y += ibv.y; gv[gg].z += ibv.z; gv[gg].w += ibv.w;
        }

        unsigned short hb[4], lb[4];
        {
            const float* gi = (const float*)&gv[0];
            const float* gf = (const float*)&gv[1];
            const float* gn = (const float*)&gv[2];
            const float* go = (const float*)&gv[3];
            float* cr = (float*)&creg;
            float* hr = (float*)&hreg;
            #pragma unroll
            for (int j = 0; j < 4; ++j) {
                float cn = sigm(gf[j]) * cr[j] + sigm(gi[j]) * tanh_fast(gn[j]);
                float hn = sigm(go[j]) * tanh_fast(cn);
                if (upd) { cr[j] = cn; hr[j] = hn; }
                split_bf16(hr[j], hb[j], lb[j]);
            }
        }
        uint2 hp, lp;
        hp.x = (unsigned)hb[0] | ((unsigned)hb[1] << 16);
        hp.y = (unsigned)hb[2] | ((unsigned)hb[3] << 16);
        lp.x = (unsigned)lb[0] | ((unsigned)lb[1] << 16);
        lp.y = (unsigned)lb[2] | ((unsigned)lb[3] << 16);
        st_h8(whh + gidx, hp);
        st_h8(whl + gidx, lp);
        if (t == 255) {
            *(float4*)(h_fin + gidx) = hreg;
            *(float4*)(c_fin + gidx) = creg;
        }
        grid_barrier(barCnt, 256u * (unsigned)(t + 1), tid);
    }
}

// ---------------------------------------------------------------------------
// bf16-split MFMA LSTM step (2-term) — used by the 16 decoder steps
// (initE = u_p, tokens/lengths = null). Unchanged from R8.
// ---------------------------------------------------------------------------
__global__ __launch_bounds__(512, 2) void lstm_step_mfma(
    const float* __restrict__ h_in,
    const ushort_t* __restrict__ hhi,
    const ushort_t* __restrict__ hlo,
    float* __restrict__ h_out,
    ushort_t* __restrict__ hhi_o,
    ushort_t* __restrict__ hlo_o,
    float* __restrict__ c_st,
    const ushort_t* __restrict__ Whi,
    const float* __restrict__ initE,
    const int* __restrict__ tokens,
    const int* __restrict__ lengths,
    int t)
{
    __shared__ __align__(16) char smem[65536];
    float* Gx = (float*)smem;

    const int tid = threadIdx.x;
    const int w = tid >> 6;
    const int g = w & 3;
    const int kh = w >> 2;
    const int l = tid & 63;
    const int q = l >> 4;
    const int fr = l & 15;

    const int id = blockIdx.x;
    const int by = (id & 7) + 8 * ((id >> 3) & 3);
    const int bx = id >> 5;
    const int fbase = bx * 64;
    const int n0 = by * 32;

    const int sgrp = tid >> 8;
    const int u = tid & 255;
    const int ar = u >> 2;
    const int s0 = u & 3;
    const size_t a_goff = (size_t)(fbase + ar) * HH + s0 * 8 + sgrp * 512;
    const int sw0 = (s0 + ar) & 7;
    const int sw1 = ((s0 + 4) + ar) & 7;
    const int lds0 = ar * 8 + sw0;
    const int lds1 = ar * 8 + sw1;

    const size_t brow0 = ((size_t)(g * HH) + n0 + fr) * HH + q * 8 + kh * 512;
    const size_t brow1 = ((size_t)(g * HH) + n0 + 16 + fr) * HH + q * 8 + kh * 512;

    floatx4 acc[4][2];
    #pragma unroll
    for (int m = 0; m < 4; ++m)
        #pragma unroll
        for (int n = 0; n < 2; ++n) acc[m][n] = (floatx4)(0.0f);

    int4 pa_h0 = *(const int4*)(hhi + a_goff);
    int4 pa_h1 = *(const int4*)(hhi + a_goff + 32);
    int4 pa_l0 = *(const int4*)(hlo + a_goff);
    int4 pa_l1 = *(const int4*)(hlo + a_goff + 32);

    short8 Bh[2][2][2];
    #pragma unroll
    for (int kk = 0; kk < 2; ++kk) {
        Bh[0][0][kk] = *(const short8*)(Whi + brow0 + kk * 32);
        Bh[0][1][kk] = *(const short8*)(Whi + brow1 + kk * 32);
    }

    {
        char* R0 = smem + sgrp * 32768;
        ((int4*)R0)[lds0] = pa_h0;
        ((int4*)R0)[lds1] = pa_h1;
        ((int4*)(R0 + 8192))[lds0] = pa_l0;
        ((int4*)(R0 + 8192))[lds1] = pa_l1;
    }
    __syncthreads();

    #pragma unroll 2
    for (int i = 0; i < 8; ++i) {
        const int cur = i & 1, nxt = cur ^ 1;
        const char* AsH = smem + (kh * 2 + cur) * 16384;
        const char* AsL = AsH + 8192;

        if (i < 7) {
            const int k0 = (i + 1) * 64;
            pa_h0 = *(const int4*)(hhi + a_goff + k0);
            pa_h1 = *(const int4*)(hhi + a_goff + k0 + 32);
            pa_l0 = *(const int4*)(hlo + a_goff + k0);
            pa_l1 = *(const int4*)(hlo + a_goff + k0 + 32);
            #pragma unroll
            for (int kk = 0; kk < 2; ++kk) {
                Bh[nxt][0][kk] = *(const short8*)(Whi + brow0 + k0 + kk * 32);
                Bh[nxt][1][kk] = *(const short8*)(Whi + brow1 + k0 + kk * 32);
            }
        }

        #pragma unroll
        for (int m = 0; m < 4; ++m) {
            const int r = m * 16 + fr;
            short8 ah0 = *(const short8*)(AsH + (r * 8 + ((0 + q + r) & 7)) * 16);
            short8 ah1 = *(const short8*)(AsH + (r * 8 + ((4 + q + r) & 7)) * 16);
            short8 al0 = *(const short8*)(AsL + (r * 8 + ((0 + q + r) & 7)) * 16);
            short8 al1 = *(const short8*)(AsL + (r * 8 + ((4 + q + r) & 7)) * 16);
            #pragma unroll
            for (int n = 0; n < 2; ++n) {
                acc[m][n] = __builtin_amdgcn_mfma_f32_16x16x32_bf16(ah0, Bh[cur][n][0], acc[m][n], 0, 0, 0);
                acc[m][n] = __builtin_amdgcn_mfma_f32_16x16x32_bf16(al0, Bh[cur][n][0], acc[m][n], 0, 0, 0);
                acc[m][n] = __builtin_amdgcn_mfma_f32_16x16x32_bf16(ah1, Bh[cur][n][1], acc[m][n], 0, 0, 0);
                acc[m][n] = __builtin_amdgcn_mfma_f32_16x16x32_bf16(al1, Bh[cur][n][1], acc[m][n], 0, 0, 0);
            }
        }

        if (i < 7) {
            char* DH = smem + (sgrp * 2 + nxt) * 16384;
            ((int4*)DH)[lds0] = pa_h0;
            ((int4*)DH)[lds1] = pa_h1;
            ((int4*)(DH + 8192))[lds0] = pa_l0;
            ((int4*)(DH + 8192))[lds1] = pa_l1;
        }
        __syncthreads();
    }

    if (kh == 1) {
        #pragma unroll
        for (int m = 0; m < 4; ++m)
            #pragma unroll
            for (int n = 0; n < 2; ++n)
                #pragma unroll
                for (int r = 0; r < 4; ++r)
                    Gx[(g * 64 + m * 16 + q * 4 + r) * 36 + n * 16 + fr] = acc[m][n][r];
    }
    __syncthreads();
    if (kh == 0) {
        #pragma unroll
        for (int m = 0; m < 4; ++m)
            #pragma unroll
            for (int n = 0; n < 2; ++n)
                #pragma unroll
                for (int r = 0; r < 4; ++r) {
                    const int idx = (g * 64 + m * 16 + q * 4 + r) * 36 + n * 16 + fr;
                    Gx[idx] += acc[m][n][r];
                }
    }
    __syncthreads();

    const int rr = tid >> 3;
    const int c0 = (tid & 7) * 4;
    const int f = fbase + rr;
    const int gc = n0 + c0;
    const size_t gidx = (size_t)f * HH + gc;
    const float* ib = tokens ? (initE + (size_t)tokens[f * LL + t] * 4096)
                             : (initE + (size_t)f * 4096);
    const bool upd = lengths ? (t < lengths[f]) : true;

    float4 gv[4];
    #pragma unroll
    for (int gg = 0; gg < 4; ++gg) {
        gv[gg] = *(const float4*)&Gx[(gg * 64 + rr) * 36 + c0];
        const float4 ibv = *(const float4*)(ib + gg * 1024 + gc);
        gv[gg].x += ibv.x; gv[gg].y += ibv.y; gv[gg].z += ibv.z; gv[gg].w += ibv.w;
    }
    const float4 coldv = *(const float4*)(c_st + gidx);
    const float4 holdv = *(const float4*)(h_in + gidx);

    float4 cw, hw;
    unsigned short hb[4], lb[4];
    {
        const float* gi = (const float*)&gv[0];
        const float* gf = (const float*)&gv[1];
        const float* gn = (const float*)&gv[2];
        const float* go = (const float*)&gv[3];
        const float* co = (const float*)&coldv;
        const float* ho = (const float*)&holdv;
        #pragma unroll
        for (int j = 0; j < 4; ++j) {
            float cn = sigm(gf[j]) * co[j] + sigm(gi[j]) * tanh_fast(gn[j]);
            float hn = sigm(go[j]) * tanh_fast(cn);
            float cv = upd ? cn : co[j];
            float hv = upd ? hn : ho[j];
            ((float*)&cw)[j] = cv;
            ((float*)&hw)[j] = hv;
            split_bf16(hv, hb[j], lb[j]);
        }
    }
    *(float4*)(c_st + gidx) = cw;
    *(float4*)(h_out + gidx) = hw;
    uint2 hp, lp;
    hp.x = (unsigned)hb[0] | ((unsigned)hb[1] << 16);
    hp.y = (unsigned)hb[2] | ((unsigned)hb[3] << 16);
    lp.x = (unsigned)lb[0] | ((unsigned)lb[1] << 16);
    lp.y = (unsigned)lb[2] | ((unsigned)lb[3] << 16);
    *(uint2*)(hhi_o + gidx) = hp;
    *(uint2*)(hlo_o + gidx) = lp;
}

// ---------------------------------------------------------------------------
// Generic fp32 C[M][N] = A[M][K] @ W[N][K]^T + bias[N]
// grid (M/32, N/64), block 256; per thread 4x2.
// ---------------------------------------------------------------------------
__global__ __launch_bounds__(256) void gemm_bias(
    const float* __restrict__ A, const float* __restrict__ W,
    const float* __restrict__ bias, float* __restrict__ C,
    int N, int K)
{
    __shared__ __align__(16) float As[16][32];
    __shared__ __align__(16) float Bs[16][64];
    const int tid = threadIdx.x;
    const int tm = tid & 7;
    const int tn = tid >> 3;
    const int m0 = blockIdx.x * 32, n0 = blockIdx.y * 64;
    const int am = tid >> 3;
    const int ak = (tid & 7) * 2;
    const int br = tid >> 2;
    const int bk = (tid & 3) * 4;
    const float* arow = A + (size_t)(m0 + am) * K;
    const float* brow = W + (size_t)(n0 + br) * K;
    float acc[4][2] = {};
    const int tm4 = tm * 4, tn2 = tn * 2;

    for (int k0 = 0; k0 < K; k0 += 16) {
        __syncthreads();
        float2 av = *(const float2*)(arow + k0 + ak);
        float4 bv = *(const float4*)(brow + k0 + bk);
        As[ak][am] = av.x; As[ak + 1][am] = av.y;
        Bs[bk][br] = bv.x; Bs[bk + 1][br] = bv.y;
        Bs[bk + 2][br] = bv.z; Bs[bk + 3][br] = bv.w;
        __syncthreads();
        #pragma unroll
        for (int k = 0; k < 16; ++k) {
            float4 a = *(const float4*)&As[k][tm4];
            float2 b = *(const float2*)&Bs[k][tn2];
            acc[0][0] += a.x * b.x; acc[0][1] += a.x * b.y;
            acc[1][0] += a.y * b.x; acc[1][1] += a.y * b.y;
            acc[2][0] += a.z * b.x; acc[2][1] += a.z * b.y;
            acc[3][0] += a.w * b.x; acc[3][1] += a.w * b.y;
        }
    }
    float b0 = bias[n0 + tn2], b1 = bias[n0 + tn2 + 1];
    #pragma unroll
    for (int mi = 0; mi < 4; ++mi) {
        float2 o;
        o.x = acc[mi][0] + b0;
        o.y = acc[mi][1] + b1;
        *(float2*)(C + (size_t)(m0 + tm4 + mi) * N + n0 + tn2) = o;
    }
}

// ---------------------------------------------------------------------------
// pooled[b][n] = tanh(max_e (h[4b+e] @ W_mp^T) + b_mp)   (tanh monotone)
// ---------------------------------------------------------------------------
__global__ __launch_bounds__(256) void mp_pool(
    const float* __restrict__ h, const float* __restrict__ Wmp,
    const float* __restrict__ bmp, float* __restrict__ pooled)
{
    __shared__ __align__(16) float As[16][32];
    __shared__ __align__(16) float Bs[16][64];
    const int tid = threadIdx.x;
    const int tm = tid & 7;
    const int tn = tid >> 3;
    const int m0 = blockIdx.x * 32, n0 = blockIdx.y * 64;
    const int am = tid >> 3;
    const int ak = (tid & 7) * 2;
    const int br = tid >> 2;
    const int bk = (tid & 3) * 4;
    const float* arow = h + (size_t)(m0 + am) * HH;
    const float* brow = Wmp + (size_t)(n0 + br) * HH;
    float acc[4][2] = {};
    const int tm4 = tm * 4, tn2 = tn * 2;

    for (int k0 = 0; k0 < HH; k0 += 16) {
        __syncthreads();
        float2 av = *(const float2*)(arow + k0 + ak);
        float4 bv = *(const float4*)(brow + k0 + bk);
        As[ak][am] = av.x; As[ak + 1][am] = av.y;
        Bs[bk][br] = bv.x; Bs[bk + 1][br] = bv.y;
        Bs[bk + 2][br] = bv.z; Bs[bk + 3][br] = bv.w;
        __syncthreads();
        #pragma unroll
        for (int k = 0; k < 16; ++k) {
            float4 a = *(const float4*)&As[k][tm4];
            float2 b = *(const float2*)&Bs[k][tn2];
            acc[0][0] += a.x * b.x; acc[0][1] += a.x * b.y;
            acc[1][0] += a.y * b.x; acc[1][1] += a.y * b.y;
            acc[2][0] += a.z * b.x; acc[2][1] += a.z * b.y;
            acc[3][0] += a.w * b.x; acc[3][1] += a.w * b.y;
        }
    }
    float mx0 = fmaxf(fmaxf(acc[0][0], acc[1][0]), fmaxf(acc[2][0], acc[3][0]));
    float mx1 = fmaxf(fmaxf(acc[0][1], acc[1][1]), fmaxf(acc[2][1], acc[3][1]));
    mx0 += bmp[n0 + tn2];
    mx1 += bmp[n0 + tn2 + 1];
    float2 o;
    o.x = tanh_fast(mx0);
    o.y = tanh_fast(mx1);
    const int bidx = (m0 >> 2) + tm;
    *(float2*)(pooled + (size_t)bidx * HH + n0 + tn2) = o;
}

extern "C" void kernel_launch(void* const* d_in, const int* in_sizes, int n_in,
                              void* d_out, int out_size, void* d_ws, size_t ws_size,
                              hipStream_t stream)
{
    const int*   tokens_in   = (const int*)d_in[0];
    const int*   lengths_in  = (const int*)d_in[1];
    const int*   tokens_out  = (const int*)d_in[2];
    const int*   lengths_out = (const int*)d_in[3];
    const float* embedding   = (const float*)d_in[4];
    const float* W_ih_in     = (const float*)d_in[5];
    const float* W_hh_in     = (const float*)d_in[6];
    const float* b_in        = (const float*)d_in[7];
    const float* W_ih_out    = (const float*)d_in[8];
    const float* W_hh_out    = (const float*)d_in[9];
    const float* b_out       = (const float*)d_in[10];
    const float* W_ih_p      = (const float*)d_in[11];
    const float* W_hh_p      = (const float*)d_in[12];
    const float* b_p         = (const float*)d_in[13];
    const float* W_mp        = (const float*)d_in[14];
    const float* b_mp        = (const float*)d_in[15];
    const float* W_sm        = (const float*)d_in[16];
    const float* b_sm        = (const float*)d_in[17];
    float* out = (float*)d_out;

    // workspace layout (float units); total ~18.5M floats = 74 MB
    float* ws = (float*)d_ws;
    float* h_a      = ws;                  // 524288
    float* h_b      = ws + 524288;         // 524288
    float* c_st     = ws + 1048576;        // 524288
    float* embW_in  = ws + 1572864;        // 524288
    float* embW_out = ws + 2097152;        // 524288
    float* u_p      = ws + 2621440;        // 2097152
    float* pooled   = ws + 4718592;        // 131072
    ushort_t* hhi_a = (ushort_t*)(ws + 4849664);   // 524288 bf16
    ushort_t* hlo_a = (ushort_t*)(ws + 5111808);
    ushort_t* hhi_b = (ushort_t*)(ws + 5373952);
    ushort_t* hlo_b = (ushort_t*)(ws + 5636096);
    ushort_t* Whi_in  = (ushort_t*)(ws + 5898240); // 4194304 bf16 each
    ushort_t* Whi_out = (ushort_t*)(ws + 10092544);
    ushort_t* Whi_p   = (ushort_t*)(ws + 14286848);
    // barrier counter (verified single counter) at u_p[0]
    unsigned* barCnt  = (unsigned*)u_p;

    // allow 160 KB dynamic LDS for the persistent encoder (host-side
    // attribute set; not a stream op -> graph-capture safe). Idempotent.
    hipFuncSetAttribute((const void*)lstm_encoder_persistent,
                        hipFuncAttributeMaxDynamicSharedMemorySize, 163840);

    // zero h0's bf16 hi/lo (hhi_a/hlo_a adjacent) + all barrier state
    fillz<<<2048, 256, 0, stream>>>(ws + 4849664, 524288);
    fillz<<<8, 256, 0, stream>>>(u_p, 2048);

    // round the three recurrent weight matrices to bf16 (hi only; 2-term)
    round_w<<<16384, 256, 0, stream>>>(W_hh_in,  Whi_in,  4194304);
    round_w<<<16384, 256, 0, stream>>>(W_hh_out, Whi_out, 4194304);
    round_w<<<16384, 256, 0, stream>>>(W_hh_p,   Whi_p,   4194304);

    // embW = embedding @ W_ih^T + b  (x @ W_ih collapses to a gather)
    gemm_bias<<<dim3(4, 64), 256, 0, stream>>>(embedding, W_ih_in, b_in, embW_in, 4096, 128);
    gemm_bias<<<dim3(4, 64), 256, 0, stream>>>(embedding, W_ih_out, b_out, embW_out, 4096, 128);

    // --- persistent cooperative encoder: both 128-step phases, one launch ---
    {
        void* kargs[] = {
            (void*)&hhi_a, (void*)&hlo_a, (void*)&hhi_b, (void*)&hlo_b,
            (void*)&h_a, (void*)&c_st,
            (void*)&Whi_in, (void*)&Whi_out,
            (void*)&embW_in, (void*)&embW_out,
            (void*)&tokens_in, (void*)&lengths_in,
            (void*)&tokens_out, (void*)&lengths_out,
            (void*)&barCnt
        };
        hipLaunchCooperativeKernel((void*)lstm_encoder_persistent,
                                   dim3(256), dim3(512), kargs, 163840, stream);
    }

    // decoder handoff: final h in h_a (fp32) + hhi_a/hlo_a (bf16), c in c_st
    float* hc = h_a;  ushort_t* hic = hhi_a;  ushort_t* loc = hlo_a;
    float* hn = h_b;  ushort_t* hin = hhi_b;  ushort_t* lon = hlo_b;

    // u_p = prev_h @ W_ih_p^T + b_p  (prev_h constant across all 16 steps)
    gemm_bias<<<dim3(16, 64), 256, 0, stream>>>(hc, W_ih_p, b_p, u_p, 4096, 1024);

    for (int t = 0; t < 16; ++t) {
        lstm_step_mfma<<<256, 512, 0, stream>>>(
            hc, hic, loc, hn, hin, lon, c_st, Whi_p, u_p,
            nullptr, nullptr, t);
        mp_pool<<<dim3(16, 16), 256, 0, stream>>>(hn, W_mp, b_mp, pooled);
        gemm_bias<<<dim3(4, 16), 256, 0, stream>>>(pooled, W_sm, b_sm,
                                                   out + (size_t)t * (BB * PP), 1024, 1024);
        float* tf = hc; hc = hn; hn = tf;
        ushort_t* th = hic; hic = hin; hin = th;
        ushort_t* tl = loc; loc = lon; lon = tl;
    }
}